// Round 3
// baseline (127.503 us; speedup 1.0000x reference)
//
#include <hip/hip_runtime.h>
#include <hip/hip_bf16.h>
#include <math.h>

// ---------------- CQT constants ----------------
#define NBINS    252
#define NFRAMES  456
#define HOPSZ    484
#define SIGLEN   220500
#define PADOFF   34688          // bf16 signal padding offset (mult of 8)
#define XBF_ELEMS 317440        // padded bf16 signal length (covers all reads, zero-filled)
#define SRD      44100.0
#define FMIND    32.70319566257483
#define TWO_PI_D 6.283185307179586476925287
#define MAXCH    288
#define MAXSEG   144
#define SEG      2              // chunks per segment (in-register K accumulation)
#define SC       32             // K-steps (x32 taps) per chunk
#define CHUNK_BYTES (SC*2048)   // 65536 B per chunk of bank
#define CHUNK_ELEMS (SC*1024)   // 32768 ushort per chunk

typedef unsigned short ushort_t;
typedef __attribute__((ext_vector_type(8))) short bf16x8;
typedef __attribute__((ext_vector_type(4))) float f32x4;

struct ChunkTab { int2 e[MAXCH]; };   // .x = group, .y = jadj (tap offset of chunk start)
struct SegTab   { int4 e[MAXSEG]; };  // .x = group, .y = c0 (global chunk idx), .z = nc, .w = jadj
struct GTab     { int2 e[16]; };      // per group: .x = seg start, .y = seg count

// ---------------- setup: bf16 padded signal + per-bin norms ----------------
__global__ __launch_bounds__(256) void setup_kernel(const float* __restrict__ sig,
                                                    ushort_t* __restrict__ xbf,
                                                    float* __restrict__ nrm) {
  int i = blockIdx.x * 256 + threadIdx.x;
  if (i < XBF_ELEMS) {
    int s = i - PADOFF;
    float v = (s >= 0 && s < SIGLEN) ? sig[s] : 0.0f;
    __hip_bfloat16 h = __float2bfloat16(v);
    xbf[i] = *reinterpret_cast<ushort_t*>(&h);
  }
  if (blockIdx.x == 0 && i < NBINS) {
    const double PI = 3.14159265358979323846;
    double freq = FMIND * exp2((double)i / 36.0);
    double Q = 1.0 / (exp2(1.0 / 36.0) - 1.0);
    double L = Q * SRD / freq;
    int T = (int)(L * 0.5);
    double N = (double)(2 * T + 1);
    double win_sum = 0.5 * N - 0.5 * (sin(PI * (N - L) / L) / sin(PI / L));
    nrm[i] = (float)(1.0 / (win_sum * sqrt(L)));
  }
}

// ---------------- kernel-bank generation, pre-swizzled to B-fragment layout ----------
// bank[c][ks][frag][lane][j] bf16 : frag0 = kr (cos), frag1 = ki (sin), un-normalized.
// lane -> (bin = 16g + (lane&15), k_local = (lane>>4)*8 + j), t = jadj + ks*32 + k_local.
__global__ __launch_bounds__(256) void gen_bank(ushort_t* __restrict__ bank, ChunkTab tab) {
  int c = blockIdx.y;
  int e = blockIdx.x * 256 + threadIdx.x;   // 0..4095
  int ks = e >> 7;
  int rem = e & 127;
  int frag = (rem >> 6) & 1;
  int lane = rem & 63;
  int bl = lane & 15, kb = lane >> 4;
  int g = tab.e[c].x, jadj = tab.e[c].y;
  int b = g * 16 + bl;
  int t0 = jadj + ks * 32 + kb * 8;

  ushort_t res[8];
#pragma unroll
  for (int j = 0; j < 8; ++j) res[j] = 0;

  if (b < NBINS) {
    double freq = FMIND * exp2((double)b / 36.0);
    double fos = freq / SRD;
    double Q = 1.0 / (exp2(1.0 / 36.0) - 1.0);
    double L = Q * SRD / freq;
    int T = (int)(L * 0.5);
    if (t0 + 7 >= -T && t0 <= T) {
      double rv = fos * (double)t0; rv -= floor(rv);
      float ang0 = (float)(rv * TWO_PI_D);
      float dang = (float)(fos * TWO_PI_D);
      float invL = (float)(1.0 / L);
#pragma unroll
      for (int j = 0; j < 8; ++j) {
        int tt = t0 + j;
        if (tt >= -T && tt <= T) {
          float win = 0.5f + 0.5f * __cosf(6.2831853f * ((float)tt * invL));
          float s, cc;
          __sincosf(ang0 + (float)j * dang, &s, &cc);
          float val = win * (frag ? s : cc);
          __hip_bfloat16 h = __float2bfloat16(val);
          res[j] = *reinterpret_cast<ushort_t*>(&h);
        }
      }
    }
  }
  union { ushort_t u[8]; uint4 v; } pk;
#pragma unroll
  for (int j = 0; j < 8; ++j) pk.u[j] = res[j];
  *reinterpret_cast<uint4*>(bank + (size_t)c * CHUNK_ELEMS + ks * 1024 + frag * 512 + lane * 8) = pk.v;
}

// ---------------- main block-sparse MFMA GEMM (atomic-free) ----------------
// grid (4 frame-supertiles, nseg), 256 thr = 4 waves.
// wave w: frames fbase = st*128 + w*32 (two 16-row A tiles), 32 cols (16 kr + 16 ki).
// Accumulates the whole segment (nc*32 K-steps) in registers, then stores
// coalesced float2 partials to a unique per-segment slot. No atomics.
__global__ __launch_bounds__(256) void cqt_mfma(const ushort_t* __restrict__ xbf,
                                                const ushort_t* __restrict__ bank,
                                                float2* __restrict__ partial,
                                                SegTab tab) {
  const int tid = threadIdx.x;
  const int lane = tid & 63;
  const int w = tid >> 6;
  const int s = blockIdx.y;
  const int c0 = tab.e[s].y;
  const int nks = tab.e[s].z * SC;
  const int jadj = tab.e[s].w;
  const int bl = lane & 15, kb = lane >> 4;
  const int fbase = blockIdx.x * 128 + w * 32;

  // A: row m = lane&15 -> frame fbase+m ; k offset kb*8 (8B-aligned: all terms %4==0 elems)
  const ushort_t* pA0 = xbf + (PADOFF + (fbase + bl) * HOPSZ + jadj + kb * 8);
  const ushort_t* pA1 = pA0 + 16 * HOPSZ;
  const ushort_t* pB  = bank + (size_t)c0 * CHUNK_ELEMS + lane * 8;

  f32x4 ar0 = {0.f, 0.f, 0.f, 0.f};
  f32x4 ai0 = ar0, ar1 = ar0, ai1 = ar0;

#pragma unroll 8
  for (int ks = 0; ks < nks; ++ks) {
    union { uint2 q[2]; bf16x8 v; } a0, a1;
    a0.q[0] = *reinterpret_cast<const uint2*>(pA0 + ks * 32);
    a0.q[1] = *reinterpret_cast<const uint2*>(pA0 + ks * 32 + 4);
    a1.q[0] = *reinterpret_cast<const uint2*>(pA1 + ks * 32);
    a1.q[1] = *reinterpret_cast<const uint2*>(pA1 + ks * 32 + 4);
    union { uint4 q; bf16x8 v; } bk, bi;
    bk.q = *reinterpret_cast<const uint4*>(pB + (size_t)ks * 1024);
    bi.q = *reinterpret_cast<const uint4*>(pB + (size_t)ks * 1024 + 512);
    ar0 = __builtin_amdgcn_mfma_f32_16x16x32_bf16(a0.v, bk.v, ar0, 0, 0, 0);
    ai0 = __builtin_amdgcn_mfma_f32_16x16x32_bf16(a0.v, bi.v, ai0, 0, 0, 0);
    ar1 = __builtin_amdgcn_mfma_f32_16x16x32_bf16(a1.v, bk.v, ar1, 0, 0, 0);
    ai1 = __builtin_amdgcn_mfma_f32_16x16x32_bf16(a1.v, bi.v, ai1, 0, 0, 0);
  }

  // C/D: col = lane&15 (bin-in-group), row = (lane>>4)*4 + reg  [m89-verified]
  // partial[s][f (0..511)][bl] float2; per (row) 16 lanes write 128B contiguous.
  float2* pp = partial + ((size_t)s * 512 + fbase) * 16 + bl;
  const int row = kb * 4;
#pragma unroll
  for (int r = 0; r < 4; ++r) {
    pp[(size_t)(row + r) * 16]        = make_float2(ar0[r], ai0[r]);
    pp[(size_t)(row + r + 16) * 16]   = make_float2(ar1[r], ai1[r]);
  }
}

// ---------------- finalize: sum partials, magnitude + per-bin norm ----------------
__global__ __launch_bounds__(256) void fin_kernel(const float2* __restrict__ partial,
                                                  const float* __restrict__ nrm,
                                                  float* __restrict__ out, GTab gt) {
  int id = blockIdx.x * 256 + threadIdx.x;
  if (id >= NBINS * NFRAMES) return;
  int b = id / NFRAMES;
  int f = id - b * NFRAMES;
  int g = b >> 4, bl = b & 15;
  int s0 = gt.e[g].x, sn = gt.e[g].y;
  float cr = 0.f, ci = 0.f;
  for (int s = s0; s < s0 + sn; ++s) {
    float2 v = partial[((size_t)s * 512 + f) * 16 + bl];
    cr += v.x; ci += v.y;
  }
  out[id] = nrm[b] * sqrtf(cr * cr + ci * ci);
}

// ---------------- launch ----------------
extern "C" void kernel_launch(void* const* d_in, const int* in_sizes, int n_in,
                              void* d_out, int out_size, void* d_ws, size_t ws_size,
                              hipStream_t stream) {
  const float* sig = (const float*)d_in[0];
  float* out = (float*)d_out;
  char* ws = (char*)d_ws;

  // host-side chunk + segment tables (pure arithmetic, identical every call)
  ChunkTab ctab; SegTab stab; GTab gtab;
  int nch = 0, nseg = 0;
  const double Q = 1.0 / (exp2(1.0 / 36.0) - 1.0);
  for (int gq = 0; gq < 16; ++gq) {
    double freq = FMIND * exp2((double)(16 * gq) / 36.0);
    double L = Q * SRD / freq;
    int T = (int)(L * 0.5);
    int r = (4 - (T & 3)) & 3;          // make tstart % 4 == 0 (8B-aligned A loads)
    int tstart = -(T + r);
    int ntaps = 2 * T + 1 + r;
    int nsteps = (ntaps + 31) / 32;     // K-steps of 32 taps
    int chunks = (nsteps + SC - 1) / SC;
    int base = nch;
    for (int k = 0; k < chunks; ++k) {
      ctab.e[nch].x = gq; ctab.e[nch].y = tstart + k * SC * 32; ++nch;
    }
    gtab.e[gq].x = nseg;
    for (int cs = 0; cs < chunks; cs += SEG) {
      int nc = (chunks - cs) < SEG ? (chunks - cs) : SEG;
      stab.e[nseg].x = gq;
      stab.e[nseg].y = base + cs;
      stab.e[nseg].z = nc;
      stab.e[nseg].w = tstart + cs * SC * 32;
      ++nseg;
    }
    gtab.e[gq].y = nseg - gtab.e[gq].x;
  }
  for (int i = nch; i < MAXCH; ++i)  { ctab.e[i].x = 0; ctab.e[i].y = 0; }
  for (int i = nseg; i < MAXSEG; ++i){ stab.e[i].x = 0; stab.e[i].y = 0; stab.e[i].z = 1; stab.e[i].w = 0; }

  // ws layout: xbf | bank (nch chunks) | partial (nseg slots) | nrm
  ushort_t* xbf  = (ushort_t*)ws;
  size_t off_bank = (size_t)XBF_ELEMS * 2;                       // 634,880
  ushort_t* bank = (ushort_t*)(ws + off_bank);
  size_t off_part = off_bank + (size_t)nch * CHUNK_BYTES;
  float2* partial = (float2*)(ws + off_part);
  size_t off_nrm = off_part + (size_t)nseg * 512 * 16 * sizeof(float2);
  float* nrm = (float*)(ws + off_nrm);

  setup_kernel<<<(XBF_ELEMS + 255) / 256, 256, 0, stream>>>(sig, xbf, nrm);
  gen_bank<<<dim3(16, nch), 256, 0, stream>>>(bank, ctab);
  cqt_mfma<<<dim3(4, nseg), 256, 0, stream>>>(xbf, bank, partial, stab);
  fin_kernel<<<(NBINS * NFRAMES + 255) / 256, 256, 0, stream>>>(partial, nrm, out, gtab);
}

// Round 4
// 121.506 us; speedup vs baseline: 1.0493x; 1.0493x over previous
//
#include <hip/hip_runtime.h>
#include <hip/hip_bf16.h>
#include <math.h>

// ---------------- CQT constants ----------------
#define NBINS    252
#define NFRAMES  456
#define HOPSZ    484
#define SIGLEN   220500
#define PADOFF   34688          // bf16 signal padding offset (mult of 8)
#define XBF_ELEMS 317440        // padded bf16 signal length (covers all reads, zero-filled)
#define SRD      44100.0
#define FMIND    32.70319566257483
#define MAXCH    264
#define SC       32             // K-steps (x32 taps) per chunk

typedef unsigned short ushort_t;
typedef __attribute__((ext_vector_type(8))) short bf16x8;
typedef __attribute__((ext_vector_type(4))) float f32x4;

struct ChunkTab { int2 e[MAXCH]; };  // .x = group, .y = jadj (tap offset of chunk start)
struct GTab     { int2 e[16]; };     // per group: .x = first chunk idx, .y = chunk count

__device__ __forceinline__ ushort_t f2bf(float x) {
  __hip_bfloat16 h = __float2bfloat16(x);
  return *reinterpret_cast<ushort_t*>(&h);
}

// ---------------- pad signal to bf16 ----------------
__global__ __launch_bounds__(256) void pad_bf16(const float* __restrict__ sig,
                                                ushort_t* __restrict__ xbf) {
  int i = blockIdx.x * 256 + threadIdx.x;
  if (i < XBF_ELEMS) {
    int s = i - PADOFF;
    float v = (s >= 0 && s < SIGLEN) ? sig[s] : 0.0f;
    xbf[i] = f2bf(v);
  }
}

// ---------------- prep: per-bin float constants + norms (doubles run ONCE, 1 block) ---
// binc[b] = {fos, invL, Tf, 0}; entries 252..255 get Tf = -1 (masks everything).
__global__ void prep_kernel(float4* __restrict__ binc, float* __restrict__ nrm) {
  int b = threadIdx.x;
  if (b >= 256) return;
  if (b < NBINS) {
    const double PI = 3.14159265358979323846;
    double freq = FMIND * exp2((double)b / 36.0);
    double fos = freq / SRD;
    double Q = 1.0 / (exp2(1.0 / 36.0) - 1.0);
    double L = Q * SRD / freq;
    int T = (int)(L * 0.5);
    double N = (double)(2 * T + 1);
    double win_sum = 0.5 * N - 0.5 * (sin(PI * (N - L) / L) / sin(PI / L));
    binc[b] = make_float4((float)fos, (float)(1.0 / L), (float)T, 0.0f);
    nrm[b] = (float)(1.0 / (win_sum * sqrt(L)));
  } else {
    binc[b] = make_float4(0.0f, 0.0f, -1.0f, 0.0f);
  }
}

// ---------------- fused: generate chunk bank in LDS, then MFMA ----------------
// grid (2 frame-halves, nch chunks), 512 threads = 8 waves.
// Phase 1: all threads generate the chunk's B fragments (32 ks x [kr 512 | ki 512] bf16)
//          into 64 KB LDS, float-only math, pre-swizzled to MFMA B layout.
// Phase 2: wave w handles frames st*256 + w*32 .. +31 (two 16-row A tiles);
//          32 K-steps of 4 MFMAs reading B from LDS, A from L2-resident signal.
// Output: per-(chunk, st) partial tile, coalesced float2 stores, no atomics.
__global__ __launch_bounds__(512) void cqt_fused(const ushort_t* __restrict__ xbf,
                                                 const float4* __restrict__ binc,
                                                 float2* __restrict__ partial,
                                                 ChunkTab tab) {
  __shared__ ushort_t blds[SC * 1024];     // 64 KB

  const int tid  = threadIdx.x;
  const int lane = tid & 63;
  const int bl   = lane & 15, kb = lane >> 4;
  const int c    = blockIdx.y;
  const int st   = blockIdx.x;
  const int g    = tab.e[c].x, jadj = tab.e[c].y;

  // ---- phase 1: bank generation (each thread: 4 ks-slabs, 8 taps each, kr+ki) ----
  {
    const float4 bc = binc[g * 16 + bl];
    const float fos = bc.x, invL = bc.y, Tf = bc.z;
    const int ksub = tid >> 6;                       // 0..7
#pragma unroll
    for (int kq = 0; kq < 4; ++kq) {
      const int ks = ksub + kq * 8;
      const int t0 = jadj + ks * 32 + kb * 8;
      union { ushort_t u[8]; uint4 v; } pr, pi;
#pragma unroll
      for (int j = 0; j < 8; ++j) {
        const float tt = (float)(t0 + j);
        float kr = 0.0f, ki = 0.0f;
        if (fabsf(tt) <= Tf) {
          float w = 0.5f + 0.5f * __cosf(6.2831853f * (tt * invL));
          float r = fos * tt; r -= rintf(r);         // phase mod 1 (|r| <= 0.5)
          float s, cc; __sincosf(6.2831853f * r, &s, &cc);
          kr = w * cc; ki = w * s;
        }
        pr.u[j] = f2bf(kr); pi.u[j] = f2bf(ki);
      }
      *reinterpret_cast<uint4*>(&blds[ks * 1024 + lane * 8])       = pr.v;
      *reinterpret_cast<uint4*>(&blds[ks * 1024 + 512 + lane * 8]) = pi.v;
    }
  }
  __syncthreads();

  // ---- phase 2: MFMA over 32 K-steps ----
  const int w = tid >> 6;
  const int fbase = st * 256 + w * 32;
  // A row = frame fbase+bl (tile0) / +16 (tile1); k offset kb*8 + ks*32.
  // All index terms %4==0 in elems except bl*HOPSZ (484*bl %8==4) -> 8B-aligned uint2 loads.
  const ushort_t* pA0 = xbf + PADOFF + (fbase + bl) * HOPSZ + jadj + kb * 8;
  const ushort_t* pA1 = pA0 + 16 * HOPSZ;

  f32x4 ar0 = {0.f, 0.f, 0.f, 0.f};
  f32x4 ai0 = ar0, ar1 = ar0, ai1 = ar0;

#pragma unroll 8
  for (int ks = 0; ks < SC; ++ks) {
    union { uint2 q[2]; bf16x8 v; } a0, a1;
    a0.q[0] = *reinterpret_cast<const uint2*>(pA0 + ks * 32);
    a0.q[1] = *reinterpret_cast<const uint2*>(pA0 + ks * 32 + 4);
    a1.q[0] = *reinterpret_cast<const uint2*>(pA1 + ks * 32);
    a1.q[1] = *reinterpret_cast<const uint2*>(pA1 + ks * 32 + 4);
    union { uint4 q; bf16x8 v; } bk, bi;
    bk.q = *reinterpret_cast<const uint4*>(&blds[ks * 1024 + lane * 8]);
    bi.q = *reinterpret_cast<const uint4*>(&blds[ks * 1024 + 512 + lane * 8]);
    ar0 = __builtin_amdgcn_mfma_f32_16x16x32_bf16(a0.v, bk.v, ar0, 0, 0, 0);
    ai0 = __builtin_amdgcn_mfma_f32_16x16x32_bf16(a0.v, bi.v, ai0, 0, 0, 0);
    ar1 = __builtin_amdgcn_mfma_f32_16x16x32_bf16(a1.v, bk.v, ar1, 0, 0, 0);
    ai1 = __builtin_amdgcn_mfma_f32_16x16x32_bf16(a1.v, bi.v, ai1, 0, 0, 0);
  }

  // C/D: col = lane&15 (bin-in-group), row = (lane>>4)*4 + reg  [m89-verified]
  // partial[(c*2+st)][frame_local 0..255][bl] float2; 16 lanes/row -> 128B contiguous.
  float2* pp = partial + ((size_t)(c * 2 + st) * 256 + w * 32) * 16 + bl;
  const int row = kb * 4;
#pragma unroll
  for (int r = 0; r < 4; ++r) {
    pp[(size_t)(row + r) * 16]      = make_float2(ar0[r], ai0[r]);
    pp[(size_t)(row + r + 16) * 16] = make_float2(ar1[r], ai1[r]);
  }
}

// ---------------- finalize: sum partials over chunks, magnitude + norm ----------------
__global__ __launch_bounds__(256) void fin_kernel(const float2* __restrict__ partial,
                                                  const float* __restrict__ nrm,
                                                  float* __restrict__ out, GTab gt) {
  int id = blockIdx.x * 256 + threadIdx.x;
  if (id >= NBINS * NFRAMES) return;
  int b = id / NFRAMES;
  int f = id - b * NFRAMES;
  int g = b >> 4, bl = b & 15;
  int st = f >> 8, fl = f & 255;
  int c0 = gt.e[g].x, nc = gt.e[g].y;
  float cr = 0.f, ci = 0.f;
  for (int c = c0; c < c0 + nc; ++c) {
    float2 v = partial[((size_t)(c * 2 + st) * 256 + fl) * 16 + bl];
    cr += v.x; ci += v.y;
  }
  out[id] = nrm[b] * sqrtf(cr * cr + ci * ci);
}

// ---------------- launch ----------------
extern "C" void kernel_launch(void* const* d_in, const int* in_sizes, int n_in,
                              void* d_out, int out_size, void* d_ws, size_t ws_size,
                              hipStream_t stream) {
  const float* sig = (const float*)d_in[0];
  float* out = (float*)d_out;
  char* ws = (char*)d_ws;

  // host-side chunk table (pure arithmetic, identical every call)
  ChunkTab ctab; GTab gtab;
  int nch = 0;
  const double Q = 1.0 / (exp2(1.0 / 36.0) - 1.0);
  for (int gq = 0; gq < 16; ++gq) {
    double freq = FMIND * exp2((double)(16 * gq) / 36.0);
    double L = Q * SRD / freq;
    int T = (int)(L * 0.5);
    int r = (4 - (T & 3)) & 3;          // tstart % 4 == 0 (8B-aligned A loads)
    int tstart = -(T + r);
    int ntaps = 2 * T + 1 + r;
    int chunks = (ntaps + SC * 32 - 1) / (SC * 32);
    gtab.e[gq].x = nch; gtab.e[gq].y = chunks;
    for (int k = 0; k < chunks; ++k) {
      ctab.e[nch].x = gq; ctab.e[nch].y = tstart + k * SC * 32; ++nch;
    }
  }
  for (int i = nch; i < MAXCH; ++i) { ctab.e[i].x = 0; ctab.e[i].y = 0; }

  // ws layout: xbf | binc(256 f4) | nrm(256 f) | partial (nch*2 tiles)
  ushort_t* xbf = (ushort_t*)ws;
  size_t off = (size_t)XBF_ELEMS * 2;            // 634,880
  float4* binc = (float4*)(ws + off);  off += 256 * sizeof(float4);
  float* nrm   = (float*)(ws + off);   off += 256 * sizeof(float);
  float2* partial = (float2*)(ws + ((off + 255) & ~(size_t)255));

  pad_bf16<<<(XBF_ELEMS + 255) / 256, 256, 0, stream>>>(sig, xbf);
  prep_kernel<<<1, 256, 0, stream>>>(binc, nrm);
  cqt_fused<<<dim3(2, nch), 512, 0, stream>>>(xbf, binc, partial, ctab);
  fin_kernel<<<(NBINS * NFRAMES + 255) / 256, 256, 0, stream>>>(partial, nrm, out, gtab);
}